// Round 6
// baseline (257.350 us; speedup 1.0000x reference)
//
#include <hip/hip_runtime.h>
#include <math.h>

#define NB 128
#define NT 512
#define NE 128
#define NNEG 64
#define NSLOT (NB * 128)   // 16384 wave-tile partials

typedef __bf16 bf16x8 __attribute__((ext_vector_type(8)));
typedef float  f32x4  __attribute__((ext_vector_type(4)));

// Wave-autonomous: one wave owns 16 rows (4 s x 4 i) x 65 logits. No LDS, no
// __syncthreads — each wave streams its own A (strided dwords from mce, f32
// kept for positives, cvt->bf16 for MFMA), B (negative rows from base, L1/L2
// reuse across waves of the same b), and epilogue. Operand mappings
// (A/B: idx=lane&15, k=quad*8+j; C: row=quad*4+reg, col=lane&15) are the
// R2-verified ones (absmax 0). One ws write per wave-tile; no atomics.
__launch_bounds__(256, 3)
__global__ void cpc_wave_kernel(const float* __restrict__ base,        // (B,T,E)
                                const float* __restrict__ mce,         // (B,T,E,4)
                                const int*  __restrict__ seq_lens,     // (B)
                                const int*  __restrict__ sample_ids,   // (B,64)
                                float* __restrict__ ws)                // (NSLOT)
{
    const int jb   = blockIdx.x;        // 0..4095
    const int tid  = threadIdx.x;
    const int w    = tid >> 6;
    const int lane = tid & 63;
    const int q    = lane >> 4;         // 0..3  e-chunk / C row-group
    const int fl   = lane & 15;         // 0..15 row (A) / col (B,C) index
    const int b    = jb >> 5;           // 32 blocks per b, consecutive
    const int g    = (jb & 31) * 4 + w; // s-group 0..127
    const int s0   = g * 4;
    const int L    = seq_lens[b];
    const int slot = b * 128 + g;
    const float LOG65 = 4.1743873f;
    const float wgt[4] = {1.f/261632.f, 1.f/261120.f, 1.f/260608.f, 1.f/260096.f};

    // Fully-masked wave-tile: analytic ln(65) per existing (s,i) position.
    if (s0 >= L) {
        if (lane == 0) {
            float c = 0.f;
            #pragma unroll
            for (int i = 1; i <= 4; ++i) {
                int cnt = min(4, max(0, (NT - i) - s0));
                c += (float)cnt * LOG65 * wgt[i - 1];
            }
            ws[slot] = c;
        }
        return;   // wave-uniform; no barriers anywhere in this kernel
    }

    const int ds = fl >> 2;            // lane's s offset within the group
    const int ki = fl & 3;             // i-1

    // negative row ids for this lane's 4 column-tiles (n = nt*16 + fl)
    int rid[4];
    #pragma unroll
    for (int nt = 0; nt < 4; ++nt)
        rid[nt] = sample_ids[b * NNEG + nt * 16 + fl];

    // A row base: mce[b][s0+ds][e][ki], e-stride = 4 floats
    const float* Arow = mce + (size_t)(b * NT + s0 + ds) * (NE * 4) + ki;
    // positive base row: base[b][s0+ds+i][:] (clamped; invalid rows excluded)
    int sp = s0 + ds + ki + 1; if (sp > NT - 1) sp = NT - 1;
    const float* Prow = base + (size_t)(b * NT + sp) * NE;

    f32x4 acc[4];
    #pragma unroll
    for (int nt = 0; nt < 4; ++nt) acc[nt] = (f32x4){0.f, 0.f, 0.f, 0.f};
    float pp = 0.f;

    #pragma unroll
    for (int ks = 0; ks < 4; ++ks) {
        const int e0 = ks * 32 + q * 8;
        // A fragment: 8 e-strided dwords; keep f32 for the positive dot
        float a[8];
        #pragma unroll
        for (int u = 0; u < 8; ++u) a[u] = Arow[(size_t)(e0 + u) * 4];
        bf16x8 af;
        #pragma unroll
        for (int u = 0; u < 8; ++u) af[u] = (__bf16)a[u];
        // positive partial over this e-chunk
        float4 p0 = *(const float4*)(Prow + e0);
        float4 p1 = *(const float4*)(Prow + e0 + 4);
        pp = fmaf(a[0], p0.x, pp); pp = fmaf(a[1], p0.y, pp);
        pp = fmaf(a[2], p0.z, pp); pp = fmaf(a[3], p0.w, pp);
        pp = fmaf(a[4], p1.x, pp); pp = fmaf(a[5], p1.y, pp);
        pp = fmaf(a[6], p1.z, pp); pp = fmaf(a[7], p1.w, pp);
        // B fragments straight from base rows + MFMA
        #pragma unroll
        for (int nt = 0; nt < 4; ++nt) {
            const float* Bp = base + (size_t)rid[nt] * NE + e0;
            float4 b0 = *(const float4*)Bp;
            float4 b1 = *(const float4*)(Bp + 4);
            bf16x8 bv;
            bv[0] = (__bf16)b0.x; bv[1] = (__bf16)b0.y;
            bv[2] = (__bf16)b0.z; bv[3] = (__bf16)b0.w;
            bv[4] = (__bf16)b1.x; bv[5] = (__bf16)b1.y;
            bv[6] = (__bf16)b1.z; bv[7] = (__bf16)b1.w;
            acc[nt] = __builtin_amdgcn_mfma_f32_16x16x32_bf16(af, bv, acc[nt], 0, 0, 0);
        }
    }

    // complete positives: sum the 4 e-chunks (lanes sharing fl across q)
    pp += __shfl_xor(pp, 16);
    pp += __shfl_xor(pp, 32);

    // epilogue: per C row (row = q*4+r), logsumexp over 64 negs + positive
    float lossacc = 0.f;
    #pragma unroll
    for (int r = 0; r < 4; ++r) {
        int row = q * 4 + r;
        int s   = s0 + (row >> 2);
        int ip  = (row & 3) + 1;
        float p = __shfl(pp, row);          // lane 'row' holds m=row, q-summed
        float z0 = acc[0][r], z1 = acc[1][r], z2 = acc[2][r], z3 = acc[3][r];
        float mx = fmaxf(fmaxf(z0, z1), fmaxf(z2, z3));
        mx = fmaxf(mx, __shfl_xor(mx, 1));
        mx = fmaxf(mx, __shfl_xor(mx, 2));
        mx = fmaxf(mx, __shfl_xor(mx, 4));
        mx = fmaxf(mx, __shfl_xor(mx, 8));
        mx = fmaxf(mx, p);
        float es = __expf(z0 - mx) + __expf(z1 - mx)
                 + __expf(z2 - mx) + __expf(z3 - mx);
        es += __shfl_xor(es, 1);
        es += __shfl_xor(es, 2);
        es += __shfl_xor(es, 4);
        es += __shfl_xor(es, 8);
        es += __expf(p - mx);
        float loss = __logf(es) + (mx - p);
        loss = (s < L) ? loss : LOG65;      // masked row => ln(65)
        bool take = (s < NT - ip) && (fl == 0);
        lossacc += take ? wgt[ip - 1] * loss : 0.f;
    }
    lossacc += __shfl_xor(lossacc, 16);     // fold the 4 q row-groups
    lossacc += __shfl_xor(lossacc, 32);
    if (lane == 0) ws[slot] = lossacc;
}

// Sum the 16384 per-wave partials -> out[0]. One block, no atomics.
__global__ void reduce_k(const float* __restrict__ ws, float* __restrict__ out) {
    const int tid = threadIdx.x;   // 256
    float s = 0.f;
    #pragma unroll
    for (int i = 0; i < NSLOT / 256; ++i) s += ws[tid + 256 * i];
    s += __shfl_xor(s, 1);
    s += __shfl_xor(s, 2);
    s += __shfl_xor(s, 4);
    s += __shfl_xor(s, 8);
    s += __shfl_xor(s, 16);
    s += __shfl_xor(s, 32);
    __shared__ float wsum[4];
    if ((tid & 63) == 0) wsum[tid >> 6] = s;
    __syncthreads();
    if (tid == 0) out[0] = wsum[0] + wsum[1] + wsum[2] + wsum[3];
}

extern "C" void kernel_launch(void* const* d_in, const int* in_sizes, int n_in,
                              void* d_out, int out_size, void* d_ws, size_t ws_size,
                              hipStream_t stream) {
    (void)in_sizes; (void)n_in; (void)out_size; (void)ws_size;
    const float* base       = (const float*)d_in[0];
    const float* mce        = (const float*)d_in[1];
    const int*   seq_lens   = (const int*)d_in[2];
    const int*   sample_ids = (const int*)d_in[3];
    float* out = (float*)d_out;
    float* ws  = (float*)d_ws;   // 16384 floats; every wave-tile writes its slot

    cpc_wave_kernel<<<dim3(NB * 32), 256, 0, stream>>>(base, mce, seq_lens, sample_ids, ws);
    reduce_k<<<1, 256, 0, stream>>>(ws, out);
}